// Round 2
// baseline (321.286 us; speedup 1.0000x reference)
//
#include <hip/hip_runtime.h>

#define NPIX (512 * 512)   // 262144
#define NB 32
#define NK 4
#define CHUNKS 64
#define TPB 256
#define CHUNK_ELEMS (NPIX / CHUNKS)          // 4096
#define V4_ITERS (CHUNK_ELEMS / (TPB * 4))   // 4

// ws layout (floats):
// [0..127]   focal_sum  (b*4+k)
// [128..255] p_sum
// [256..383] inter
// [384..511] m_sum
// [512..639] mi
// [640..671] t_sum (per b)
#define WS_FLOATS 672

__global__ __launch_bounds__(TPB, 8) void sam_loss_pass1(
    const float* __restrict__ x, const float* __restrict__ t,
    float* __restrict__ ws) {
  const int blk = blockIdx.x;
  const int b = blk / CHUNKS;
  const int c = blk % CHUNKS;

  const float4* __restrict__ t4 =
      (const float4*)(t + (size_t)b * NPIX + (size_t)c * CHUNK_ELEMS);
  const float4* __restrict__ x40 =
      (const float4*)(x + (size_t)b * NK * NPIX + (size_t)c * CHUNK_ELEMS);
  const float4* __restrict__ x41 = x40 + NPIX / 4;
  const float4* __restrict__ x42 = x40 + 2 * (NPIX / 4);
  const float4* __restrict__ x43 = x40 + 3 * (NPIX / 4);

  float fs[NK] = {0.f, 0.f, 0.f, 0.f};
  float ps[NK] = {0.f, 0.f, 0.f, 0.f};
  float is_[NK] = {0.f, 0.f, 0.f, 0.f};
  // count accumulators stay uniform -> SGPRs (ballot/popc path)
  unsigned int msc[NK] = {0u, 0u, 0u, 0u};
  unsigned int misc[NK] = {0u, 0u, 0u, 0u};
  unsigned int tsc = 0u;

  for (int it = 0; it < V4_ITERS; ++it) {
    const int i = it * TPB + threadIdx.x;
    const float4 tv = t4[i];
    const float4 xv0 = x40[i];
    const float4 xv1 = x41[i];
    const float4 xv2 = x42[i];
    const float4 xv3 = x43[i];
    const float tt[4] = {tv.x, tv.y, tv.z, tv.w};
    const float xx[NK][4] = {{xv0.x, xv0.y, xv0.z, xv0.w},
                             {xv1.x, xv1.y, xv1.z, xv1.w},
                             {xv2.x, xv2.y, xv2.z, xv2.w},
                             {xv3.x, xv3.y, xv3.z, xv3.w}};
#pragma unroll
    for (int j = 0; j < 4; ++j) {
      const bool tpos = tt[j] != 0.0f;  // targets are exactly 0.0 or 1.0
      const unsigned long long tb = __ballot(tpos);
      tsc += (unsigned)__popcll(tb);
#pragma unroll
      for (int k = 0; k < NK; ++k) {
        const float xf = xx[k][j];
        const bool pos = xf >= 0.0f;
        const unsigned long long pb = __ballot(pos);
        msc[k] += (unsigned)__popcll(pb);
        misc[k] += (unsigned)__popcll(pb & tb);
        const float ax = fabsf(xf);
        const float e = __expf(-ax);                      // exp(-|x|) in (0,1]
        const float r = __builtin_amdgcn_rcpf(1.0f + e);  // sigmoid(|x|)
        const float l1 = __logf(1.0f + e);                // log1p(e)
        const float er = e * r;                           // sigmoid(-|x|)
        const bool mx = pos != tpos;
        const float bce = (mx ? ax : 0.0f) + l1;
        const float om = mx ? r : er;  // 1 - exp(-bce)
        fs[k] += om * om * bce;
        const float sp = pos ? r : er;  // sigmoid(x)
        ps[k] += sp;
        if (tpos) is_[k] += sp;
      }
    }
  }

  // thread -> wave -> block -> global reduction
  __shared__ float red[TPB / 64][21];
  const int lane = threadIdx.x & 63;
  const int wid = threadIdx.x >> 6;

  float fvals[12];
#pragma unroll
  for (int k = 0; k < NK; ++k) {
    fvals[k] = fs[k];
    fvals[4 + k] = ps[k];
    fvals[8 + k] = is_[k];
  }
#pragma unroll
  for (int j = 0; j < 12; ++j) {
    float v = fvals[j];
#pragma unroll
    for (int off = 32; off > 0; off >>= 1) v += __shfl_down(v, off, 64);
    if (lane == 0) red[wid][j] = v;
  }
  if (lane == 0) {
#pragma unroll
    for (int k = 0; k < NK; ++k) {
      red[wid][12 + k] = (float)msc[k];
      red[wid][16 + k] = (float)misc[k];
    }
    red[wid][20] = (float)tsc;
  }
  __syncthreads();
  if (threadIdx.x < 21) {
    const int j = threadIdx.x;
    const float v = red[0][j] + red[1][j] + red[2][j] + red[3][j];
    int off;
    if (j < 12) {
      off = (j >> 2) * (NB * NK) + b * NK + (j & 3);
    } else if (j < 20) {
      off = (3 + ((j - 12) >> 2)) * (NB * NK) + b * NK + (j & 3);
    } else {
      off = 5 * (NB * NK) + b;
    }
    atomicAdd(ws + off, v);
  }
}

__global__ __launch_bounds__(64) void sam_loss_pass2(
    const float* __restrict__ ws, const float* __restrict__ ious,
    float* __restrict__ out) {
  const float AREA_LO[4] = {0.04f, 0.0f, 0.01f, 0.16f};
  const float AREA_HI[4] = {0.64f, 0.04f, 0.25f, 1.0f};
  const float S = 1e-4f;
  const int lane = threadIdx.x;

  float pf = 0.f, pd = 0.f, pi = 0.f, sv = 0.f;
  if (lane < NB) {
    const int b = lane;
    const float tsum = ws[5 * (NB * NK) + b];
    const float ratio = tsum / (float)NPIX;
    float cnt = 0.f, sf = 0.f, sd = 0.f, si = 0.f;
#pragma unroll
    for (int k = 0; k < NK; ++k) {
      const bool valid = (ratio > AREA_LO[k]) && (ratio < AREA_HI[k]);
      if (valid) {
        const int idx = b * NK + k;
        const float focal = 0.8f * ws[idx] / (float)NPIX;
        const float psum = ws[1 * (NB * NK) + idx];
        const float inter = ws[2 * (NB * NK) + idx];
        const float msum = ws[3 * (NB * NK) + idx];
        const float mi = ws[4 * (NB * NK) + idx];
        const float dice = 1.0f - (2.0f * inter + S) / (psum + tsum + S);
        const float iou_gt = (mi + S) / (msum + tsum - mi + S);
        const float d = ious[idx] - iou_gt;
        cnt += 1.0f;
        sf += focal;
        sd += dice;
        si += d * d;
      }
    }
    if (cnt > 0.f) {
      pf = sf / cnt;
      pd = sd / cnt;
      pi = si / cnt;
      sv = 1.0f;
    }
  }
#pragma unroll
  for (int off = 32; off > 0; off >>= 1) {
    pf += __shfl_down(pf, off, 64);
    pd += __shfl_down(pd, off, 64);
    pi += __shfl_down(pi, off, 64);
    sv += __shfl_down(sv, off, 64);
  }
  if (lane == 0) {
    const float inv = sv > 0.f ? 1.0f / sv : 1.0f;
    out[0] = 20.0f * pf * inv;
    out[1] = pd * inv;
    out[2] = pi * inv;
  }
}

extern "C" void kernel_launch(void* const* d_in, const int* in_sizes, int n_in,
                              void* d_out, int out_size, void* d_ws,
                              size_t ws_size, hipStream_t stream) {
  const float* pred_masks = (const float*)d_in[0];
  const float* pred_ious = (const float*)d_in[1];
  const float* targets = (const float*)d_in[2];
  float* out = (float*)d_out;
  float* ws = (float*)d_ws;

  hipMemsetAsync(ws, 0, WS_FLOATS * sizeof(float), stream);
  sam_loss_pass1<<<NB * CHUNKS, TPB, 0, stream>>>(pred_masks, targets, ws);
  sam_loss_pass2<<<1, 64, 0, stream>>>(ws, pred_ious, out);
}

// Round 3
// 226.228 us; speedup vs baseline: 1.4202x; 1.4202x over previous
//
#include <hip/hip_runtime.h>

#define NPIX (512 * 512)  // 262144
#define NB 32
#define NK 4
#define TPB 256
#define CPB 64                      // chunks per (b,k)
#define CHUNK (NPIX / CPB)          // 4096 elems
#define T4PT (CHUNK / (TPB * 4))    // 4 float4 per thread per input

// ws layout (floats):
// [0..127]   focal_sum  (b*4+k)
// [128..255] p_sum
// [256..383] inter
// [384..511] m_sum
// [512..639] mi
// [640..671] t_sum (per b)
#define WS_FLOATS 672

__global__ __launch_bounds__(TPB, 8) void sam_loss_pass1(
    const float* __restrict__ x, const float* __restrict__ t,
    float* __restrict__ ws) {
  const int blk = blockIdx.x;        // ((b*CPB + c)*NK + k)
  const int k = blk & (NK - 1);
  const int bc = blk >> 2;
  const int b = bc / CPB;
  const int c = bc % CPB;

  const float4* __restrict__ t4 =
      (const float4*)(t + (size_t)b * NPIX + (size_t)c * CHUNK);
  const float4* __restrict__ x4 =
      (const float4*)(x + ((size_t)b * NK + k) * NPIX + (size_t)c * CHUNK);

  // issue all 8 loads up front (8 KB/wave in flight)
  float4 xv[T4PT], tv[T4PT];
#pragma unroll
  for (int it = 0; it < T4PT; ++it) {
    const int i = it * TPB + threadIdx.x;
    xv[it] = x4[i];
    tv[it] = t4[i];
  }

  float fs = 0.f, ps = 0.f, is_ = 0.f, ms = 0.f, mi = 0.f, ts = 0.f;
#pragma unroll
  for (int it = 0; it < T4PT; ++it) {
    const float xx[4] = {xv[it].x, xv[it].y, xv[it].z, xv[it].w};
    const float tt[4] = {tv[it].x, tv[it].y, tv[it].z, tv[it].w};
#pragma unroll
    for (int j = 0; j < 4; ++j) {
      const float xf = xx[j];
      const float tf = tt[j];                            // exactly 0.0 or 1.0
      const float ax = fabsf(xf);
      const float e = __expf(-ax);                       // exp(-|x|) in (0,1]
      const float denom = 1.0f + e;
      const float r = __builtin_amdgcn_rcpf(denom);      // sigmoid(|x|)
      const float l1 = __logf(denom);                    // log1p(e)
      const float er = e * r;                            // sigmoid(-|x|)
      const bool pos = xf >= 0.0f;
      const bool tpos = tf != 0.0f;
      const bool mx = pos != tpos;
      const float bce = (mx ? ax : 0.0f) + l1;           // t?sp(-x):sp(x)
      const float om = mx ? r : er;                      // 1 - exp(-bce)
      fs = fmaf(om * om, bce, fs);
      const float sp = pos ? r : er;                     // sigmoid(x)
      ps += sp;
      is_ = fmaf(sp, tf, is_);
      const float mf = pos ? 1.0f : 0.0f;
      ms += mf;
      mi = fmaf(mf, tf, mi);
      ts += tf;
    }
  }

  // thread -> wave -> block -> global reduction of 6 values
  __shared__ float red[TPB / 64][6];
  const int lane = threadIdx.x & 63;
  const int wid = threadIdx.x >> 6;
  float vals[6] = {fs, ps, is_, ms, mi, ts};
#pragma unroll
  for (int j = 0; j < 6; ++j) {
    float v = vals[j];
#pragma unroll
    for (int off = 32; off > 0; off >>= 1) v += __shfl_down(v, off, 64);
    if (lane == 0) red[wid][j] = v;
  }
  __syncthreads();
  if (threadIdx.x < 6) {
    const int j = threadIdx.x;
    const float v = red[0][j] + red[1][j] + red[2][j] + red[3][j];
    if (j < 5) {
      atomicAdd(ws + j * (NB * NK) + b * NK + k, v);
    } else if (k == 0) {
      atomicAdd(ws + 5 * (NB * NK) + b, v);
    }
  }
}

__global__ __launch_bounds__(64) void sam_loss_pass2(
    const float* __restrict__ ws, const float* __restrict__ ious,
    float* __restrict__ out) {
  const float AREA_LO[4] = {0.04f, 0.0f, 0.01f, 0.16f};
  const float AREA_HI[4] = {0.64f, 0.04f, 0.25f, 1.0f};
  const float S = 1e-4f;
  const int lane = threadIdx.x;

  float pf = 0.f, pd = 0.f, pi = 0.f, sv = 0.f;
  if (lane < NB) {
    const int b = lane;
    const float tsum = ws[5 * (NB * NK) + b];
    const float ratio = tsum / (float)NPIX;
    float cnt = 0.f, sf = 0.f, sd = 0.f, si = 0.f;
#pragma unroll
    for (int k = 0; k < NK; ++k) {
      const bool valid = (ratio > AREA_LO[k]) && (ratio < AREA_HI[k]);
      if (valid) {
        const int idx = b * NK + k;
        const float focal = 0.8f * ws[idx] / (float)NPIX;
        const float psum = ws[1 * (NB * NK) + idx];
        const float inter = ws[2 * (NB * NK) + idx];
        const float msum = ws[3 * (NB * NK) + idx];
        const float mi = ws[4 * (NB * NK) + idx];
        const float dice = 1.0f - (2.0f * inter + S) / (psum + tsum + S);
        const float iou_gt = (mi + S) / (msum + tsum - mi + S);
        const float d = ious[idx] - iou_gt;
        cnt += 1.0f;
        sf += focal;
        sd += dice;
        si += d * d;
      }
    }
    if (cnt > 0.f) {
      pf = sf / cnt;
      pd = sd / cnt;
      pi = si / cnt;
      sv = 1.0f;
    }
  }
#pragma unroll
  for (int off = 32; off > 0; off >>= 1) {
    pf += __shfl_down(pf, off, 64);
    pd += __shfl_down(pd, off, 64);
    pi += __shfl_down(pi, off, 64);
    sv += __shfl_down(sv, off, 64);
  }
  if (lane == 0) {
    const float inv = sv > 0.f ? 1.0f / sv : 1.0f;
    out[0] = 20.0f * pf * inv;
    out[1] = pd * inv;
    out[2] = pi * inv;
  }
}

extern "C" void kernel_launch(void* const* d_in, const int* in_sizes, int n_in,
                              void* d_out, int out_size, void* d_ws,
                              size_t ws_size, hipStream_t stream) {
  const float* pred_masks = (const float*)d_in[0];
  const float* pred_ious = (const float*)d_in[1];
  const float* targets = (const float*)d_in[2];
  float* out = (float*)d_out;
  float* ws = (float*)d_ws;

  hipMemsetAsync(ws, 0, WS_FLOATS * sizeof(float), stream);
  sam_loss_pass1<<<NB * NK * CPB, TPB, 0, stream>>>(pred_masks, targets, ws);
  sam_loss_pass2<<<1, 64, 0, stream>>>(ws, pred_ious, out);
}

// Round 4
// 224.404 us; speedup vs baseline: 1.4317x; 1.0081x over previous
//
#include <hip/hip_runtime.h>

#define NPIX (512 * 512)  // 262144
#define NB 32
#define NK 4
#define TPB 256
#define CPB 64                      // chunks per (b,k)
#define CHUNK (NPIX / CPB)          // 4096 elems
#define T4PT (CHUNK / (TPB * 4))    // 4 float4 per thread per input

// ws layout (floats):
// [0..127]   focal_sum  (b*4+k)
// [128..255] p_sum
// [256..383] inter
// [384..511] m_sum
// [512..639] mi
// [640..671] t_sum (per b)
#define WS_FLOATS 672

__global__ __launch_bounds__(TPB, 8) void sam_loss_pass1(
    const float* __restrict__ x, const float* __restrict__ t,
    float* __restrict__ ws) {
  // XCD-aware swizzle: the 4 k-siblings of one (b,c) chunk differ by 8 in
  // blockIdx -> same XCD (round-robin %8) -> t-chunk fetched once into that
  // XCD's L2, reused by the other 3 blocks.
  const int blk = blockIdx.x;            // (bc>>3)*32 + k*8 + (bc&7)
  const int low = blk & 7;
  const int k = (blk >> 3) & 3;
  const int bc = ((blk >> 5) << 3) | low;
  const int b = bc >> 6;                 // bc / CPB
  const int c = bc & (CPB - 1);          // bc % CPB

  const float4* __restrict__ t4 =
      (const float4*)(t + (size_t)b * NPIX + (size_t)c * CHUNK);
  const float4* __restrict__ x4 =
      (const float4*)(x + ((size_t)b * NK + k) * NPIX + (size_t)c * CHUNK);

  // issue all 8 loads up front (8 KB/wave in flight)
  float4 xv[T4PT], tv[T4PT];
#pragma unroll
  for (int it = 0; it < T4PT; ++it) {
    const int i = it * TPB + threadIdx.x;
    xv[it] = x4[i];
    tv[it] = t4[i];
  }

  float fs = 0.f, ps = 0.f, is_ = 0.f, ms = 0.f, mi = 0.f, ts = 0.f;
#pragma unroll
  for (int it = 0; it < T4PT; ++it) {
    const float xx[4] = {xv[it].x, xv[it].y, xv[it].z, xv[it].w};
    const float tt[4] = {tv[it].x, tv[it].y, tv[it].z, tv[it].w};
#pragma unroll
    for (int j = 0; j < 4; ++j) {
      const float xf = xx[j];
      const float tf = tt[j];                            // exactly 0.0 or 1.0
      const float ax = fabsf(xf);
      const float e = __expf(-ax);                       // exp(-|x|) in (0,1]
      const float denom = 1.0f + e;
      const float r = __builtin_amdgcn_rcpf(denom);      // sigmoid(|x|)
      const float l1 = __logf(denom);                    // log1p(e)
      const float er = e * r;                            // sigmoid(-|x|)
      const bool pos = xf >= 0.0f;
      const bool tpos = tf != 0.0f;
      const bool mx = pos != tpos;
      const float bce = (mx ? ax : 0.0f) + l1;           // t?sp(-x):sp(x)
      const float om = mx ? r : er;                      // 1 - exp(-bce)
      fs = fmaf(om * om, bce, fs);
      const float sp = pos ? r : er;                     // sigmoid(x)
      ps += sp;
      is_ = fmaf(sp, tf, is_);
      const float mf = pos ? 1.0f : 0.0f;
      ms += mf;
      mi = fmaf(mf, tf, mi);
      ts += tf;
    }
  }

  // thread -> wave -> block -> global reduction of 6 values
  __shared__ float red[TPB / 64][6];
  const int lane = threadIdx.x & 63;
  const int wid = threadIdx.x >> 6;
  float vals[6] = {fs, ps, is_, ms, mi, ts};
#pragma unroll
  for (int j = 0; j < 6; ++j) {
    float v = vals[j];
#pragma unroll
    for (int off = 32; off > 0; off >>= 1) v += __shfl_down(v, off, 64);
    if (lane == 0) red[wid][j] = v;
  }
  __syncthreads();
  if (threadIdx.x < 6) {
    const int j = threadIdx.x;
    const float v = red[0][j] + red[1][j] + red[2][j] + red[3][j];
    if (j < 5) {
      atomicAdd(ws + j * (NB * NK) + b * NK + k, v);
    } else if (k == 0) {
      atomicAdd(ws + 5 * (NB * NK) + b, v);
    }
  }
}

__global__ __launch_bounds__(64) void sam_loss_pass2(
    const float* __restrict__ ws, const float* __restrict__ ious,
    float* __restrict__ out) {
  const float AREA_LO[4] = {0.04f, 0.0f, 0.01f, 0.16f};
  const float AREA_HI[4] = {0.64f, 0.04f, 0.25f, 1.0f};
  const float S = 1e-4f;
  const int lane = threadIdx.x;

  float pf = 0.f, pd = 0.f, pi = 0.f, sv = 0.f;
  if (lane < NB) {
    const int b = lane;
    const float tsum = ws[5 * (NB * NK) + b];
    const float ratio = tsum / (float)NPIX;
    float cnt = 0.f, sf = 0.f, sd = 0.f, si = 0.f;
#pragma unroll
    for (int k = 0; k < NK; ++k) {
      const bool valid = (ratio > AREA_LO[k]) && (ratio < AREA_HI[k]);
      if (valid) {
        const int idx = b * NK + k;
        const float focal = 0.8f * ws[idx] / (float)NPIX;
        const float psum = ws[1 * (NB * NK) + idx];
        const float inter = ws[2 * (NB * NK) + idx];
        const float msum = ws[3 * (NB * NK) + idx];
        const float mi = ws[4 * (NB * NK) + idx];
        const float dice = 1.0f - (2.0f * inter + S) / (psum + tsum + S);
        const float iou_gt = (mi + S) / (msum + tsum - mi + S);
        const float d = ious[idx] - iou_gt;
        cnt += 1.0f;
        sf += focal;
        sd += dice;
        si += d * d;
      }
    }
    if (cnt > 0.f) {
      pf = sf / cnt;
      pd = sd / cnt;
      pi = si / cnt;
      sv = 1.0f;
    }
  }
#pragma unroll
  for (int off = 32; off > 0; off >>= 1) {
    pf += __shfl_down(pf, off, 64);
    pd += __shfl_down(pd, off, 64);
    pi += __shfl_down(pi, off, 64);
    sv += __shfl_down(sv, off, 64);
  }
  if (lane == 0) {
    const float inv = sv > 0.f ? 1.0f / sv : 1.0f;
    out[0] = 20.0f * pf * inv;
    out[1] = pd * inv;
    out[2] = pi * inv;
  }
}

extern "C" void kernel_launch(void* const* d_in, const int* in_sizes, int n_in,
                              void* d_out, int out_size, void* d_ws,
                              size_t ws_size, hipStream_t stream) {
  const float* pred_masks = (const float*)d_in[0];
  const float* pred_ious = (const float*)d_in[1];
  const float* targets = (const float*)d_in[2];
  float* out = (float*)d_out;
  float* ws = (float*)d_ws;

  hipMemsetAsync(ws, 0, WS_FLOATS * sizeof(float), stream);
  sam_loss_pass1<<<NB * NK * CPB, TPB, 0, stream>>>(pred_masks, targets, ws);
  sam_loss_pass2<<<1, 64, 0, stream>>>(ws, pred_ious, out);
}